// Round 12
// baseline (127.808 us; speedup 1.0000x reference)
//
#include <hip/hip_runtime.h>
#include <cstdint>
#include <cstddef>

#define NH 16
#define DK 64
#define DM 1024
#define SEQL 2048
#define NB 2
#define NR (NB * SEQL)   // 4096 token rows

typedef short bf16x8 __attribute__((ext_vector_type(8)));
typedef float f32x4 __attribute__((ext_vector_type(4)));

static __device__ __forceinline__ float bf2f(short u) {
  union { unsigned int i; float f; } x;
  x.i = ((unsigned int)(unsigned short)u) << 16;
  return x.f;
}
static __device__ __forceinline__ short f2bf(float f) {
  union { unsigned int i; float f; } x;
  x.f = f;
  unsigned int r = x.i + 0x7fffu + ((x.i >> 16) & 1u);  // RNE
  return (short)(r >> 16);
}
// HW packed f32->bf16 (RNE): lo16 = bf16(a), hi16 = bf16(b)
static __device__ __forceinline__ unsigned cvtpk(float a, float b) {
  unsigned r;
  asm("v_cvt_pk_bf16_f32 %0, %1, %2" : "=v"(r) : "v"(a), "v"(b));
  return r;
}

// async global->LDS, 16B per lane; lds base wave-uniform (HW adds lane*16)
static __device__ __forceinline__ void gload16(const short* g, short* l) {
  __builtin_amdgcn_global_load_lds((const __attribute__((address_space(1))) void*)g,
                                   (__attribute__((address_space(3))) void*)l, 16, 0, 0);
}

// ---------------- all fp32 -> bf16 converts in one launch ----------------
__global__ void cvt_all(const float* __restrict__ x, const float* __restrict__ w0,
                        const float* __restrict__ w1, const float* __restrict__ w2,
                        const float* __restrict__ w3, short* __restrict__ xb,
                        short* __restrict__ o0, short* __restrict__ o1,
                        short* __restrict__ o2, short* __restrict__ o3) {
  int y = blockIdx.y;
  const float* in;
  short* out;
  if (y < 4) { in = x + (size_t)y * DM * DM; out = xb + (size_t)y * DM * DM; }
  else if (y == 4) { in = w0; out = o0; }
  else if (y == 5) { in = w1; out = o1; }
  else if (y == 6) { in = w2; out = o2; }
  else { in = w3; out = o3; }
  int i = (blockIdx.x * blockDim.x + threadIdx.x) * 4;
  float4 v = *reinterpret_cast<const float4*>(in + i);
  short4 o;
  o.x = f2bf(v.x); o.y = f2bf(v.y); o.z = f2bf(v.z); o.w = f2bf(v.w);
  *reinterpret_cast<short4*>(out + i) = o;
}

// ---------------- RoPE cos/sin table: [2048 pos][32 freq] ----------------
__global__ void rope_table_kernel(float2* __restrict__ tab) {
  int idx = blockIdx.x * blockDim.x + threadIdx.x;  // pos*32 + j
  int pos = idx >> 5, j = idx & 31;
  float freq = powf(10000.0f, -(float)j / 32.0f);   // theta^(-2j/64)
  float ang = (float)pos * freq;
  tab[idx] = make_float2(cosf(ang), sinf(ang));
}

// ---------------- RoPE apply, vectorized bf16x8 (4 pairs/thread) ----------------
// Q additionally pre-scaled by 0.125*log2(e) (softmax works in exp2 domain).
__global__ void rope_apply_kernel(short* __restrict__ Qb, short* __restrict__ Kb,
                                  const int* __restrict__ pos, const float2* __restrict__ tab) {
  short* buf = blockIdx.y ? Kb : Qb;
  const float scale = blockIdx.y ? 1.0f : 0.1803368801f;  // 0.125*log2e
  int gid = blockIdx.x * blockDim.x + threadIdx.x;        // [0, NR*DM/8)
  int elem = gid * 8;
  int row = elem >> 10, off = elem & 1023;
  int j0 = (off & 63) >> 1;
  short* ptr = buf + (size_t)row * DM + off;
  bf16x8 v = *reinterpret_cast<bf16x8*>(ptr);
  const float2* tp = &tab[pos[row] * 32 + j0];
  bf16x8 o;
#pragma unroll
  for (int q = 0; q < 4; ++q) {
    float2 cs = tp[q];
    float xe = bf2f(v[2 * q]), xo = bf2f(v[2 * q + 1]);
    o[2 * q] = f2bf((xe * cs.x - xo * cs.y) * scale);
    o[2 * q + 1] = f2bf((xe * cs.y + xo * cs.x) * scale);
  }
  *reinterpret_cast<bf16x8*>(ptr) = o;
}

// ---------------- V transpose: V[b*S+s][h*64+d] -> Vt[(bh*64+d)][s] ----------------
// LDS tile, chunk-XOR swizzle, both global sides coalesced.
__global__ __launch_bounds__(256) void vt_transpose_kernel(const short* __restrict__ V,
                                                           short* __restrict__ Vt) {
  __shared__ short tile[64][64];
  const int t = threadIdx.x;
  const int bh = blockIdx.y, b = bh >> 4, h = bh & 15;
  const int st = blockIdx.x * 64;
#pragma unroll
  for (int p = 0; p < 2; ++p) {
    int c = p * 256 + t;
    int srow = c >> 3, ch = c & 7;
    int chs = ch ^ ((srow >> 3) & 7);  // swizzle chunk index
    *reinterpret_cast<bf16x8*>(&tile[srow][chs * 8]) =
        *reinterpret_cast<const bf16x8*>(&V[(size_t)(b * SEQL + st + srow) * DM + h * 64 + ch * 8]);
  }
  __syncthreads();
#pragma unroll
  for (int p = 0; p < 2; ++p) {
    int c = p * 256 + t;
    int drow = c >> 3, soff = (c & 7) * 8;
    short o[8];
#pragma unroll
    for (int e = 0; e < 8; ++e) {
      int srow = soff + e;
      int col = (((drow >> 3) ^ ((srow >> 3) & 7)) << 3) + (drow & 7);
      o[e] = tile[srow][col];
    }
    *reinterpret_cast<bf16x8*>(&Vt[(size_t)(bh * DK + drow) * SEQL + st + soff]) =
        *reinterpret_cast<bf16x8*>(o);
  }
}

// ---------------- bf16 GEMM core (m97 structure), acc left in registers ----------------
static __device__ __forceinline__ void gemm_core(const short* __restrict__ A,
                                                 const short* __restrict__ B,
                                                 int m0, int n0, int K,
                                                 f32x4 (&acc)[4][4]) {
  __shared__ short As[128][32];
  __shared__ short Bs[128][32];
  const int t = threadIdx.x;
  const int wid = t >> 6, lane = t & 63;
  const int wr = wid >> 1, wc = wid & 1;
  const int lrow = lane & 15, lk = lane >> 4;

#pragma unroll
  for (int i = 0; i < 4; ++i)
#pragma unroll
    for (int j = 0; j < 4; ++j) acc[i][j] = (f32x4){0.f, 0.f, 0.f, 0.f};

  for (int k0 = 0; k0 < K; k0 += 32) {
    __syncthreads();
#pragma unroll
    for (int p = 0; p < 2; ++p) {
      int c = p * 256 + t;
      int row = c >> 2, kc = (c & 3) * 8;
      gload16(&A[(size_t)(m0 + row) * K + k0 + kc], &As[0][0] + (size_t)(p * 256 + wid * 64) * 8);
      gload16(&B[(size_t)(n0 + row) * K + k0 + kc], &Bs[0][0] + (size_t)(p * 256 + wid * 64) * 8);
    }
    __syncthreads();
    bf16x8 af[4], bfr[4];
#pragma unroll
    for (int i = 0; i < 4; ++i) {
      af[i] = *reinterpret_cast<const bf16x8*>(&As[wr * 64 + i * 16 + lrow][lk * 8]);
      bfr[i] = *reinterpret_cast<const bf16x8*>(&Bs[wc * 64 + i * 16 + lrow][lk * 8]);
    }
    __builtin_amdgcn_s_setprio(1);
#pragma unroll
    for (int i = 0; i < 4; ++i)
#pragma unroll
      for (int j = 0; j < 4; ++j)
        acc[i][j] = __builtin_amdgcn_mfma_f32_16x16x32_bf16(af[i], bfr[j], acc[i][j], 0, 0, 0);
    __builtin_amdgcn_s_setprio(0);
  }
}

// ---------------- QKV GEMM; plain coalesced bf16 stores ----------------
// grid 768 flat; XCD-aware decode: each XCD owns 3 fixed B-panels (L2-resident).
__global__ __launch_bounds__(256) void qkv_gemm_kernel(
    const short* __restrict__ X, const short* __restrict__ Wq, const short* __restrict__ Wk,
    const short* __restrict__ Wv, short* __restrict__ Qb, short* __restrict__ Kb,
    short* __restrict__ Vb) {
  const int lin = blockIdx.x;           // 0..767
  const int xcd = lin & 7, i = lin >> 3;  // i 0..95
  const int nb = xcd * 3 + (i % 3);     // 0..23; same-XCD blocks share 3 B-panels
  const int my = i / 3;                 // 0..31
  const short* Bw = (nb < 8) ? Wq : (nb < 16) ? Wk : Wv;
  short* C = (nb < 8) ? Qb : (nb < 16) ? Kb : Vb;
  const int m0 = my * 128, n0 = (nb & 7) * 128;
  f32x4 acc[4][4];
  gemm_core(X, Bw, m0, n0, DM, acc);

  const int t = threadIdx.x;
  const int wid = t >> 6, lane = t & 63;
  const int wr = wid >> 1, wc = wid & 1;
  const int lrow = lane & 15, lk = lane >> 4;
#pragma unroll
  for (int i2 = 0; i2 < 4; ++i2)
#pragma unroll
    for (int j = 0; j < 4; ++j) {
      int row = m0 + wr * 64 + i2 * 16 + lk * 4;
      int col = n0 + wc * 64 + j * 16 + lrow;
#pragma unroll
      for (int r = 0; r < 4; ++r) C[(size_t)(row + r) * DM + col] = f2bf(acc[i2][j][r]);
    }
}

// grid 256 flat; each XCD owns exactly one B-panel.
__global__ __launch_bounds__(256) void out_gemm_kernel(const short* __restrict__ A,
                                                       const short* __restrict__ W,
                                                       float* __restrict__ C) {
  const int lin = blockIdx.x;  // 0..255
  const int m0 = (lin >> 3) * 128, n0 = (lin & 7) * 128;
  f32x4 acc[4][4];
  gemm_core(A, W, m0, n0, DM, acc);
  const int t = threadIdx.x;
  const int wid = t >> 6, lane = t & 63;
  const int wr = wid >> 1, wc = wid & 1;
  const int lrow = lane & 15, lk = lane >> 4;
#pragma unroll
  for (int i = 0; i < 4; ++i)
#pragma unroll
    for (int j = 0; j < 4; ++j) {
      int row = m0 + wr * 64 + i * 16 + lk * 4;
      int col = n0 + wc * 64 + j * 16 + lrow;
#pragma unroll
      for (int r = 0; r < 4; ++r) C[(size_t)(row + r) * DM + col] = acc[i][j][r];
    }
}

// ---------------- causal flash attention ----------------
// grid 512 x 512thr (8 waves). One 128-row q-tile per block. Complement dispatch.
// Swapped QK^T, exp2 domain, fixed-shift softmax (no max tracking), lsum via
// ones-column MFMA. DOUBLE-BUFFERED K/V -> ONE barrier per k-tile: write next
// tile into buf[cur^1] (whose readers finished before the PREVIOUS trailing
// barrier), then one trailing __syncthreads makes it visible.
__global__ __launch_bounds__(512) void attn_kernel(const short* __restrict__ Q,
                                                   const short* __restrict__ K,
                                                   const short* __restrict__ Vt,
                                                   short* __restrict__ O) {
  __shared__ short Ks[2][64][72];
  __shared__ short Vs[2][64][72];
  __shared__ short Ps[8][16][72];
  const int t = threadIdx.x;
  const int wid = t >> 6, lane = t & 63;
  const int lrow = lane & 15, lk = lane >> 4;
  const int lin = blockIdx.x;            // 0..511
  const int xcd = lin & 7, idx = lin >> 3;  // idx 0..63
  // long blocks (qt 15..8) dispatch first; complement (qt 0..7) second
  const int qt = (idx < 32) ? (15 - (idx >> 2)) : ((idx - 32) >> 2);
  const int bh = xcd * 4 + (idx & 3);    // 4 bh per XCD (K/V/Q fit L2)
  const int b = bh >> 4, h = bh & 15;
  const size_t base = (size_t)b * SEQL * DM + (size_t)h * DK;  // Q,K,O
  const size_t vbase = (size_t)bh * DK * SEQL;                 // Vt
  const int kr = t >> 3, ko = (t & 7) * 8;  // staging: 1 chunk/thread (512 thr = 64x64)
  const int ktmax = 2 * qt + 1;
  const int qmin = qt * 128 + wid * 16;
  const int dkt = qmin >> 6;   // wave's diagonal k-tile

  bf16x8 aq[2];
#pragma unroll
  for (int c = 0; c < 2; ++c)
    aq[c] = *reinterpret_cast<const bf16x8*>(
        &Q[base + (size_t)(qmin + lrow) * DM + c * 32 + lk * 8]);

  // ones B-fragment for the row-sum MFMA
  bf16x8 vones;
#pragma unroll
  for (int e = 0; e < 8; ++e) vones[e] = (short)0x3F80;

  f32x4 oacc[4];
#pragma unroll
  for (int g = 0; g < 4; ++g) oacc[g] = (f32x4){0.f, 0.f, 0.f, 0.f};
  f32x4 oaccL = (f32x4){0.f, 0.f, 0.f, 0.f};  // row-sum (lsum) accumulator

  // prologue: stage tile 0 into buf 0
  {
    bf16x8 k0 = *reinterpret_cast<const bf16x8*>(&K[base + (size_t)kr * DM + ko]);
    bf16x8 v0 = *reinterpret_cast<const bf16x8*>(&Vt[vbase + (size_t)kr * SEQL + ko]);
    *reinterpret_cast<bf16x8*>(&Ks[0][kr][ko]) = k0;
    *reinterpret_cast<bf16x8*>(&Vs[0][kr][ko]) = v0;
  }
  __syncthreads();
  int cur = 0;
  bf16x8 kreg, vreg;
  for (int kt = 0; kt <= ktmax; ++kt) {
    // buf[cur] holds tile kt (visible since last barrier)
    if (kt < ktmax) {  // T14: issue next tile's loads; latency hides under compute
      size_t kof = (size_t)(kt + 1) * 64;
      kreg = *reinterpret_cast<const bf16x8*>(&K[base + (kof + kr) * DM + ko]);
      vreg = *reinterpret_cast<const bf16x8*>(&Vt[vbase + (size_t)kr * SEQL + kof + ko]);
    }
    if (kt <= dkt) {  // wave-uniform active gate
      // S^T = K Q^T : lane holds S[q=qmin+lrow][k=kt*64+g*16+lk*4+r] (exp2 domain)
      f32x4 st[4];
      __builtin_amdgcn_s_setprio(1);
#pragma unroll
      for (int g = 0; g < 4; ++g) {
        bf16x8 kf0 = *reinterpret_cast<const bf16x8*>(&Ks[cur][g * 16 + lrow][lk * 8]);
        bf16x8 kf1 = *reinterpret_cast<const bf16x8*>(&Ks[cur][g * 16 + lrow][32 + lk * 8]);
        f32x4 z = (f32x4){0.f, 0.f, 0.f, 0.f};
        z = __builtin_amdgcn_mfma_f32_16x16x32_bf16(kf0, aq[0], z, 0, 0, 0);
        st[g] = __builtin_amdgcn_mfma_f32_16x16x32_bf16(kf1, aq[1], z, 0, 0, 0);
      }
      __builtin_amdgcn_s_setprio(0);
      const int qg = qmin + lrow;
      if (kt == dkt) {  // diagonal tile masking
#pragma unroll
        for (int g = 0; g < 4; ++g)
#pragma unroll
          for (int r = 0; r < 4; ++r)
            if (kt * 64 + g * 16 + lk * 4 + r > qg) st[g][r] = -1e30f;
      }
      // P = exp2(st) directly (no shift, no max tracking)
#pragma unroll
      for (int g = 0; g < 4; ++g)
#pragma unroll
        for (int r = 0; r < 4; ++r) st[g][r] = exp2f(st[g][r]);
      // P -> per-wave LDS slice -> A-frag
#pragma unroll
      for (int g = 0; g < 4; ++g) {
        uint2 wv = make_uint2(cvtpk(st[g][0], st[g][1]), cvtpk(st[g][2], st[g][3]));
        *reinterpret_cast<uint2*>(&Ps[wid][lrow][g * 16 + lk * 4]) = wv;
      }
      asm volatile("s_waitcnt lgkmcnt(0)" ::: "memory");
      __builtin_amdgcn_sched_barrier(0);
      bf16x8 pa0 = *reinterpret_cast<const bf16x8*>(&Ps[wid][lrow][lk * 8]);
      bf16x8 pa1 = *reinterpret_cast<const bf16x8*>(&Ps[wid][lrow][32 + lk * 8]);
      __builtin_amdgcn_s_setprio(1);
#pragma unroll
      for (int g = 0; g < 4; ++g) {
        bf16x8 vf0 = *reinterpret_cast<const bf16x8*>(&Vs[cur][g * 16 + lrow][lk * 8]);
        bf16x8 vf1 = *reinterpret_cast<const bf16x8*>(&Vs[cur][g * 16 + lrow][32 + lk * 8]);
        oacc[g] = __builtin_amdgcn_mfma_f32_16x16x32_bf16(pa0, vf0, oacc[g], 0, 0, 0);
        oacc[g] = __builtin_amdgcn_mfma_f32_16x16x32_bf16(pa1, vf1, oacc[g], 0, 0, 0);
      }
      // row-sum of P via ones-column MFMA -> lsum in accumulator layout
      oaccL = __builtin_amdgcn_mfma_f32_16x16x32_bf16(pa0, vones, oaccL, 0, 0, 0);
      oaccL = __builtin_amdgcn_mfma_f32_16x16x32_bf16(pa1, vones, oaccL, 0, 0, 0);
      __builtin_amdgcn_s_setprio(0);
    }
    if (kt < ktmax) {  // write next tile into the idle buffer (safe pre-barrier)
      *reinterpret_cast<bf16x8*>(&Ks[cur ^ 1][kr][ko]) = kreg;
      *reinterpret_cast<bf16x8*>(&Vs[cur ^ 1][kr][ko]) = vreg;
    }
    __syncthreads();  // single barrier: publishes buf[cur^1], retires buf[cur] readers
    cur ^= 1;
  }
  // epilogue: normalize — lsum already per-row in oaccL[r], no cross-lane ops
  float lr[4];
#pragma unroll
  for (int r = 0; r < 4; ++r) lr[r] = 1.0f / oaccL[r];
#pragma unroll
  for (int g = 0; g < 4; ++g)
#pragma unroll
    for (int r = 0; r < 4; ++r)
      O[base + (size_t)(qmin + lk * 4 + r) * DM + g * 16 + lrow] = f2bf(oacc[g][r] * lr[r]);
}

// ---------------- host launch ----------------
extern "C" void kernel_launch(void* const* d_in, const int* in_sizes, int n_in,
                              void* d_out, int out_size, void* d_ws, size_t ws_size,
                              hipStream_t stream) {
  const float* x = (const float*)d_in[0];
  const float* wq = (const float*)d_in[1];
  const float* wk = (const float*)d_in[2];
  const float* wv = (const float*)d_in[3];
  const float* wo = (const float*)d_in[4];
  const int* tpos = (const int*)d_in[5];
  float* out = (float*)d_out;

  char* w = (char*)d_ws;
  short* xb = (short*)w;  w += (size_t)NR * DM * 2;
  short* wqb = (short*)w; w += (size_t)DM * DM * 2;
  short* wkb = (short*)w; w += (size_t)DM * DM * 2;
  short* wvb = (short*)w; w += (size_t)DM * DM * 2;
  short* wob = (short*)w; w += (size_t)DM * DM * 2;
  short* Qb = (short*)w;  w += (size_t)NR * DM * 2;
  short* Kb = (short*)w;  w += (size_t)NR * DM * 2;
  short* Vb = (short*)w;  w += (size_t)NR * DM * 2;
  short* Ob = (short*)w;  w += (size_t)NR * DM * 2;
  float2* tab = (float2*)w;
  short* Vtb = xb;  // alias: xb's last use is qkv_gemm; Vt produced after

  rope_table_kernel<<<2048 * 32 / 256, 256, 0, stream>>>(tab);
  cvt_all<<<dim3(DM * DM / 1024, 8), 256, 0, stream>>>(x, wq, wk, wv, wo, xb, wqb, wkb, wvb, wob);
  qkv_gemm_kernel<<<768, 256, 0, stream>>>(xb, wqb, wkb, wvb, Qb, Kb, Vb);
  rope_apply_kernel<<<dim3(NR * DM / 8 / 256, 2), 256, 0, stream>>>(Qb, Kb, tpos, tab);
  vt_transpose_kernel<<<dim3(SEQL / 64, NB * NH), 256, 0, stream>>>(Vb, Vtb);
  attn_kernel<<<512, 512, 0, stream>>>(Qb, Kb, Vtb, Ob);
  out_gemm_kernel<<<256, 256, 0, stream>>>(Ob, wob, out);
}

// Round 16
// 119.604 us; speedup vs baseline: 1.0686x; 1.0686x over previous
//
#include <hip/hip_runtime.h>
#include <cstdint>
#include <cstddef>

#define NH 16
#define DK 64
#define DM 1024
#define SEQL 2048
#define NB 2
#define NR (NB * SEQL)   // 4096 token rows

typedef short bf16x8 __attribute__((ext_vector_type(8)));
typedef float f32x4 __attribute__((ext_vector_type(4)));

static __device__ __forceinline__ float bf2f(short u) {
  union { unsigned int i; float f; } x;
  x.i = ((unsigned int)(unsigned short)u) << 16;
  return x.f;
}
static __device__ __forceinline__ short f2bf(float f) {
  union { unsigned int i; float f; } x;
  x.f = f;
  unsigned int r = x.i + 0x7fffu + ((x.i >> 16) & 1u);  // RNE
  return (short)(r >> 16);
}
// HW packed f32->bf16 (RNE): lo16 = bf16(a), hi16 = bf16(b)
static __device__ __forceinline__ unsigned cvtpk(float a, float b) {
  unsigned r;
  asm("v_cvt_pk_bf16_f32 %0, %1, %2" : "=v"(r) : "v"(a), "v"(b));
  return r;
}

// async global->LDS, 16B per lane; lds base wave-uniform (HW adds lane*16)
static __device__ __forceinline__ void gload16(const short* g, short* l) {
  __builtin_amdgcn_global_load_lds((const __attribute__((address_space(1))) void*)g,
                                   (__attribute__((address_space(3))) void*)l, 16, 0, 0);
}

// ---------------- fp32 -> bf16 converts + RoPE table in one launch ----------------
// grid (1024, 9): y<4 -> x slices, y 4..7 -> weights, y==8 -> cos/sin table.
__global__ void cvt_all(const float* __restrict__ x, const float* __restrict__ w0,
                        const float* __restrict__ w1, const float* __restrict__ w2,
                        const float* __restrict__ w3, short* __restrict__ xb,
                        short* __restrict__ o0, short* __restrict__ o1,
                        short* __restrict__ o2, short* __restrict__ o3,
                        float2* __restrict__ tab) {
  int y = blockIdx.y;
  if (y == 8) {  // RoPE cos/sin table: [2048 pos][32 freq]
    if (blockIdx.x < 256) {
      int idx = blockIdx.x * 256 + threadIdx.x;  // pos*32 + j
      int pos = idx >> 5, j = idx & 31;
      float freq = powf(10000.0f, -(float)j / 32.0f);  // theta^(-2j/64)
      float ang = (float)pos * freq;
      tab[idx] = make_float2(cosf(ang), sinf(ang));
    }
    return;
  }
  const float* in;
  short* out;
  if (y < 4) { in = x + (size_t)y * DM * DM; out = xb + (size_t)y * DM * DM; }
  else if (y == 4) { in = w0; out = o0; }
  else if (y == 5) { in = w1; out = o1; }
  else if (y == 6) { in = w2; out = o2; }
  else { in = w3; out = o3; }
  int i = (blockIdx.x * blockDim.x + threadIdx.x) * 4;
  float4 v = *reinterpret_cast<const float4*>(in + i);
  short4 o;
  o.x = f2bf(v.x); o.y = f2bf(v.y); o.z = f2bf(v.z); o.w = f2bf(v.w);
  *reinterpret_cast<short4*>(out + i) = o;
}

// ---------------- RoPE apply, vectorized bf16x8 (4 pairs/thread) ----------------
// Q additionally pre-scaled by 0.125*log2(e) (softmax works in exp2 domain).
__global__ void rope_apply_kernel(short* __restrict__ Qb, short* __restrict__ Kb,
                                  const int* __restrict__ pos, const float2* __restrict__ tab) {
  short* buf = blockIdx.y ? Kb : Qb;
  const float scale = blockIdx.y ? 1.0f : 0.1803368801f;  // 0.125*log2e
  int gid = blockIdx.x * blockDim.x + threadIdx.x;        // [0, NR*DM/8)
  int elem = gid * 8;
  int row = elem >> 10, off = elem & 1023;
  int j0 = (off & 63) >> 1;
  short* ptr = buf + (size_t)row * DM + off;
  bf16x8 v = *reinterpret_cast<bf16x8*>(ptr);
  const float2* tp = &tab[pos[row] * 32 + j0];
  bf16x8 o;
#pragma unroll
  for (int q = 0; q < 4; ++q) {
    float2 cs = tp[q];
    float xe = bf2f(v[2 * q]), xo = bf2f(v[2 * q + 1]);
    o[2 * q] = f2bf((xe * cs.x - xo * cs.y) * scale);
    o[2 * q + 1] = f2bf((xe * cs.y + xo * cs.x) * scale);
  }
  *reinterpret_cast<bf16x8*>(ptr) = o;
}

// ---------------- V transpose: V[b*S+s][h*64+d] -> Vt[(bh*64+d)][s] ----------------
__global__ __launch_bounds__(256) void vt_transpose_kernel(const short* __restrict__ V,
                                                           short* __restrict__ Vt) {
  __shared__ short tile[64][64];
  const int t = threadIdx.x;
  const int bh = blockIdx.y, b = bh >> 4, h = bh & 15;
  const int st = blockIdx.x * 64;
#pragma unroll
  for (int p = 0; p < 2; ++p) {
    int c = p * 256 + t;
    int srow = c >> 3, ch = c & 7;
    int chs = ch ^ ((srow >> 3) & 7);  // swizzle chunk index
    *reinterpret_cast<bf16x8*>(&tile[srow][chs * 8]) =
        *reinterpret_cast<const bf16x8*>(&V[(size_t)(b * SEQL + st + srow) * DM + h * 64 + ch * 8]);
  }
  __syncthreads();
#pragma unroll
  for (int p = 0; p < 2; ++p) {
    int c = p * 256 + t;
    int drow = c >> 3, soff = (c & 7) * 8;
    short o[8];
#pragma unroll
    for (int e = 0; e < 8; ++e) {
      int srow = soff + e;
      int col = (((drow >> 3) ^ ((srow >> 3) & 7)) << 3) + (drow & 7);
      o[e] = tile[srow][col];
    }
    *reinterpret_cast<bf16x8*>(&Vt[(size_t)(bh * DK + drow) * SEQL + st + soff]) =
        *reinterpret_cast<bf16x8*>(o);
  }
}

// ---------------- bf16 GEMM core: BK=64 on the PASSED 2-syncthreads template ----------------
// Parameter change only (two-lane discipline): same single-buffer structure and the
// proven [128][32] LDS layout, but TWO half-tiles As[2]/Bs[2] staged per barrier pair
// -> 16 barrier events instead of 32 (the latency-bound qkv's dominant cost).
static __device__ __forceinline__ void gemm_core(const short* __restrict__ A,
                                                 const short* __restrict__ B,
                                                 int m0, int n0, int K,
                                                 f32x4 (&acc)[4][4]) {
  __shared__ short As[2][128][32];
  __shared__ short Bs[2][128][32];
  const int t = threadIdx.x;
  const int wid = t >> 6, lane = t & 63;
  const int wr = wid >> 1, wc = wid & 1;
  const int lrow = lane & 15, lk = lane >> 4;

#pragma unroll
  for (int i = 0; i < 4; ++i)
#pragma unroll
    for (int j = 0; j < 4; ++j) acc[i][j] = (f32x4){0.f, 0.f, 0.f, 0.f};

  for (int k0 = 0; k0 < K; k0 += 64) {
    __syncthreads();
#pragma unroll
    for (int hp = 0; hp < 2; ++hp)
#pragma unroll
      for (int p = 0; p < 2; ++p) {
        int c = p * 256 + t;            // 512 chunks of 8 bf16 = 128x32 per half
        int row = c >> 2, kc = (c & 3) * 8;
        gload16(&A[(size_t)(m0 + row) * K + k0 + hp * 32 + kc],
                &As[hp][0][0] + (size_t)(p * 256 + wid * 64) * 8);
        gload16(&B[(size_t)(n0 + row) * K + k0 + hp * 32 + kc],
                &Bs[hp][0][0] + (size_t)(p * 256 + wid * 64) * 8);
      }
    __syncthreads();
#pragma unroll
    for (int hp = 0; hp < 2; ++hp) {
      bf16x8 af[4], bfr[4];
#pragma unroll
      for (int i = 0; i < 4; ++i) {
        af[i] = *reinterpret_cast<const bf16x8*>(&As[hp][wr * 64 + i * 16 + lrow][lk * 8]);
        bfr[i] = *reinterpret_cast<const bf16x8*>(&Bs[hp][wc * 64 + i * 16 + lrow][lk * 8]);
      }
      __builtin_amdgcn_s_setprio(1);
#pragma unroll
      for (int i = 0; i < 4; ++i)
#pragma unroll
        for (int j = 0; j < 4; ++j)
          acc[i][j] = __builtin_amdgcn_mfma_f32_16x16x32_bf16(af[i], bfr[j], acc[i][j], 0, 0, 0);
      __builtin_amdgcn_s_setprio(0);
    }
  }
}

// ---------------- QKV GEMM; plain coalesced bf16 stores ----------------
// grid 768 flat; XCD-aware decode: each XCD owns 3 fixed B-panels (L2-resident).
__global__ __launch_bounds__(256) void qkv_gemm_kernel(
    const short* __restrict__ X, const short* __restrict__ Wq, const short* __restrict__ Wk,
    const short* __restrict__ Wv, short* __restrict__ Qb, short* __restrict__ Kb,
    short* __restrict__ Vb) {
  const int lin = blockIdx.x;             // 0..767
  const int xcd = lin & 7, i = lin >> 3;  // i 0..95
  const int nb = xcd * 3 + (i % 3);       // 0..23
  const int my = i / 3;                   // 0..31
  const short* Bw = (nb < 8) ? Wq : (nb < 16) ? Wk : Wv;
  short* C = (nb < 8) ? Qb : (nb < 16) ? Kb : Vb;
  const int m0 = my * 128, n0 = (nb & 7) * 128;
  f32x4 acc[4][4];
  gemm_core(X, Bw, m0, n0, DM, acc);

  const int t = threadIdx.x;
  const int wid = t >> 6, lane = t & 63;
  const int wr = wid >> 1, wc = wid & 1;
  const int lrow = lane & 15, lk = lane >> 4;
#pragma unroll
  for (int i2 = 0; i2 < 4; ++i2)
#pragma unroll
    for (int j = 0; j < 4; ++j) {
      int row = m0 + wr * 64 + i2 * 16 + lk * 4;
      int col = n0 + wc * 64 + j * 16 + lrow;
#pragma unroll
      for (int r = 0; r < 4; ++r) C[(size_t)(row + r) * DM + col] = f2bf(acc[i2][j][r]);
    }
}

// grid 256 flat; each XCD owns exactly one B-panel.
__global__ __launch_bounds__(256) void out_gemm_kernel(const short* __restrict__ A,
                                                       const short* __restrict__ W,
                                                       float* __restrict__ C) {
  const int lin = blockIdx.x;  // 0..255
  const int m0 = (lin >> 3) * 128, n0 = (lin & 7) * 128;
  f32x4 acc[4][4];
  gemm_core(A, W, m0, n0, DM, acc);
  const int t = threadIdx.x;
  const int wid = t >> 6, lane = t & 63;
  const int wr = wid >> 1, wc = wid & 1;
  const int lrow = lane & 15, lk = lane >> 4;
#pragma unroll
  for (int i = 0; i < 4; ++i)
#pragma unroll
    for (int j = 0; j < 4; ++j) {
      int row = m0 + wr * 64 + i * 16 + lk * 4;
      int col = n0 + wc * 64 + j * 16 + lrow;
#pragma unroll
      for (int r = 0; r < 4; ++r) C[(size_t)(row + r) * DM + col] = acc[i][j][r];
    }
}

// ---------------- causal flash attention (round-12 PASSED version, verbatim) ----------------
// grid 512 x 512thr (8 waves). One 128-row q-tile per block. Complement dispatch.
// Swapped QK^T, exp2 domain, fixed-shift softmax (no max tracking), lsum via
// ones-column MFMA. Dbuf K/V (register-staged) + one __syncthreads per k-tile.
__global__ __launch_bounds__(512) void attn_kernel(const short* __restrict__ Q,
                                                   const short* __restrict__ K,
                                                   const short* __restrict__ Vt,
                                                   short* __restrict__ O) {
  __shared__ short Ks[2][64][72];
  __shared__ short Vs[2][64][72];
  __shared__ short Ps[8][16][72];
  const int t = threadIdx.x;
  const int wid = t >> 6, lane = t & 63;
  const int lrow = lane & 15, lk = lane >> 4;
  const int lin = blockIdx.x;            // 0..511
  const int xcd = lin & 7, idx = lin >> 3;  // idx 0..63
  // long blocks (qt 15..8) dispatch first; complement (qt 0..7) second
  const int qt = (idx < 32) ? (15 - (idx >> 2)) : ((idx - 32) >> 2);
  const int bh = xcd * 4 + (idx & 3);    // 4 bh per XCD (K/V/Q fit L2)
  const int b = bh >> 4, h = bh & 15;
  const size_t base = (size_t)b * SEQL * DM + (size_t)h * DK;  // Q,K,O
  const size_t vbase = (size_t)bh * DK * SEQL;                 // Vt
  const int kr = t >> 3, ko = (t & 7) * 8;  // staging: 1 chunk/thread (512 thr = 64x64)
  const int ktmax = 2 * qt + 1;
  const int qmin = qt * 128 + wid * 16;
  const int dkt = qmin >> 6;   // wave's diagonal k-tile

  bf16x8 aq[2];
#pragma unroll
  for (int c = 0; c < 2; ++c)
    aq[c] = *reinterpret_cast<const bf16x8*>(
        &Q[base + (size_t)(qmin + lrow) * DM + c * 32 + lk * 8]);

  // ones B-fragment for the row-sum MFMA
  bf16x8 vones;
#pragma unroll
  for (int e = 0; e < 8; ++e) vones[e] = (short)0x3F80;

  f32x4 oacc[4];
#pragma unroll
  for (int g = 0; g < 4; ++g) oacc[g] = (f32x4){0.f, 0.f, 0.f, 0.f};
  f32x4 oaccL = (f32x4){0.f, 0.f, 0.f, 0.f};  // row-sum (lsum) accumulator

  // prologue: stage tile 0 into buf 0
  {
    bf16x8 k0 = *reinterpret_cast<const bf16x8*>(&K[base + (size_t)kr * DM + ko]);
    bf16x8 v0 = *reinterpret_cast<const bf16x8*>(&Vt[vbase + (size_t)kr * SEQL + ko]);
    *reinterpret_cast<bf16x8*>(&Ks[0][kr][ko]) = k0;
    *reinterpret_cast<bf16x8*>(&Vs[0][kr][ko]) = v0;
  }
  __syncthreads();
  int cur = 0;
  bf16x8 kreg, vreg;
  for (int kt = 0; kt <= ktmax; ++kt) {
    // buf[cur] holds tile kt (visible since last barrier)
    if (kt < ktmax) {  // T14: issue next tile's loads; latency hides under compute
      size_t kof = (size_t)(kt + 1) * 64;
      kreg = *reinterpret_cast<const bf16x8*>(&K[base + (kof + kr) * DM + ko]);
      vreg = *reinterpret_cast<const bf16x8*>(&Vt[vbase + (size_t)kr * SEQL + kof + ko]);
    }
    if (kt <= dkt) {  // wave-uniform active gate
      // S^T = K Q^T : lane holds S[q=qmin+lrow][k=kt*64+g*16+lk*4+r] (exp2 domain)
      f32x4 st[4];
      __builtin_amdgcn_s_setprio(1);
#pragma unroll
      for (int g = 0; g < 4; ++g) {
        bf16x8 kf0 = *reinterpret_cast<const bf16x8*>(&Ks[cur][g * 16 + lrow][lk * 8]);
        bf16x8 kf1 = *reinterpret_cast<const bf16x8*>(&Ks[cur][g * 16 + lrow][32 + lk * 8]);
        f32x4 z = (f32x4){0.f, 0.f, 0.f, 0.f};
        z = __builtin_amdgcn_mfma_f32_16x16x32_bf16(kf0, aq[0], z, 0, 0, 0);
        st[g] = __builtin_amdgcn_mfma_f32_16x16x32_bf16(kf1, aq[1], z, 0, 0, 0);
      }
      __builtin_amdgcn_s_setprio(0);
      const int qg = qmin + lrow;
      if (kt == dkt) {  // diagonal tile masking
#pragma unroll
        for (int g = 0; g < 4; ++g)
#pragma unroll
          for (int r = 0; r < 4; ++r)
            if (kt * 64 + g * 16 + lk * 4 + r > qg) st[g][r] = -1e30f;
      }
      // P = exp2(st) directly (no shift, no max tracking)
#pragma unroll
      for (int g = 0; g < 4; ++g)
#pragma unroll
        for (int r = 0; r < 4; ++r) st[g][r] = exp2f(st[g][r]);
      // P -> per-wave LDS slice -> A-frag
#pragma unroll
      for (int g = 0; g < 4; ++g) {
        uint2 wv = make_uint2(cvtpk(st[g][0], st[g][1]), cvtpk(st[g][2], st[g][3]));
        *reinterpret_cast<uint2*>(&Ps[wid][lrow][g * 16 + lk * 4]) = wv;
      }
      asm volatile("s_waitcnt lgkmcnt(0)" ::: "memory");
      __builtin_amdgcn_sched_barrier(0);
      bf16x8 pa0 = *reinterpret_cast<const bf16x8*>(&Ps[wid][lrow][lk * 8]);
      bf16x8 pa1 = *reinterpret_cast<const bf16x8*>(&Ps[wid][lrow][32 + lk * 8]);
      __builtin_amdgcn_s_setprio(1);
#pragma unroll
      for (int g = 0; g < 4; ++g) {
        bf16x8 vf0 = *reinterpret_cast<const bf16x8*>(&Vs[cur][g * 16 + lrow][lk * 8]);
        bf16x8 vf1 = *reinterpret_cast<const bf16x8*>(&Vs[cur][g * 16 + lrow][32 + lk * 8]);
        oacc[g] = __builtin_amdgcn_mfma_f32_16x16x32_bf16(pa0, vf0, oacc[g], 0, 0, 0);
        oacc[g] = __builtin_amdgcn_mfma_f32_16x16x32_bf16(pa1, vf1, oacc[g], 0, 0, 0);
      }
      // row-sum of P via ones-column MFMA -> lsum in accumulator layout
      oaccL = __builtin_amdgcn_mfma_f32_16x16x32_bf16(pa0, vones, oaccL, 0, 0, 0);
      oaccL = __builtin_amdgcn_mfma_f32_16x16x32_bf16(pa1, vones, oaccL, 0, 0, 0);
      __builtin_amdgcn_s_setprio(0);
    }
    if (kt < ktmax) {  // write next tile into the idle buffer (safe pre-barrier)
      *reinterpret_cast<bf16x8*>(&Ks[cur ^ 1][kr][ko]) = kreg;
      *reinterpret_cast<bf16x8*>(&Vs[cur ^ 1][kr][ko]) = vreg;
    }
    __syncthreads();  // single barrier: publishes buf[cur^1], retires buf[cur] readers
    cur ^= 1;
  }
  // epilogue: normalize — lsum already per-row in oaccL[r], no cross-lane ops
  float lr[4];
#pragma unroll
  for (int r = 0; r < 4; ++r) lr[r] = 1.0f / oaccL[r];
#pragma unroll
  for (int g = 0; g < 4; ++g)
#pragma unroll
    for (int r = 0; r < 4; ++r)
      O[base + (size_t)(qmin + lk * 4 + r) * DM + g * 16 + lrow] = f2bf(oacc[g][r] * lr[r]);
}

// ---------------- host launch ----------------
extern "C" void kernel_launch(void* const* d_in, const int* in_sizes, int n_in,
                              void* d_out, int out_size, void* d_ws, size_t ws_size,
                              hipStream_t stream) {
  const float* x = (const float*)d_in[0];
  const float* wq = (const float*)d_in[1];
  const float* wk = (const float*)d_in[2];
  const float* wv = (const float*)d_in[3];
  const float* wo = (const float*)d_in[4];
  const int* tpos = (const int*)d_in[5];
  float* out = (float*)d_out;

  char* w = (char*)d_ws;
  short* xb = (short*)w;  w += (size_t)NR * DM * 2;
  short* wqb = (short*)w; w += (size_t)DM * DM * 2;
  short* wkb = (short*)w; w += (size_t)DM * DM * 2;
  short* wvb = (short*)w; w += (size_t)DM * DM * 2;
  short* wob = (short*)w; w += (size_t)DM * DM * 2;
  short* Qb = (short*)w;  w += (size_t)NR * DM * 2;
  short* Kb = (short*)w;  w += (size_t)NR * DM * 2;
  short* Vb = (short*)w;  w += (size_t)NR * DM * 2;
  short* Ob = (short*)w;  w += (size_t)NR * DM * 2;
  float2* tab = (float2*)w;
  short* Vtb = xb;  // alias: xb's last use is qkv_gemm; Vt produced after

  cvt_all<<<dim3(DM * DM / 1024, 9), 256, 0, stream>>>(x, wq, wk, wv, wo, xb, wqb, wkb, wvb,
                                                       wob, tab);
  qkv_gemm_kernel<<<768, 256, 0, stream>>>(xb, wqb, wkb, wvb, Qb, Kb, Vb);
  rope_apply_kernel<<<dim3(NR * DM / 8 / 256, 2), 256, 0, stream>>>(Qb, Kb, tpos, tab);
  vt_transpose_kernel<<<dim3(SEQL / 64, NB * NH), 256, 0, stream>>>(Vb, Vtb);
  attn_kernel<<<512, 512, 0, stream>>>(Qb, Kb, Vtb, Ob);
  out_gemm_kernel<<<256, 256, 0, stream>>>(Ob, wob, out);
}

// Round 17
// 116.594 us; speedup vs baseline: 1.0962x; 1.0258x over previous
//
#include <hip/hip_runtime.h>
#include <cstdint>
#include <cstddef>

#define NH 16
#define DK 64
#define DM 1024
#define SEQL 2048
#define NB 2
#define NR (NB * SEQL)   // 4096 token rows

typedef short bf16x8 __attribute__((ext_vector_type(8)));
typedef float f32x4 __attribute__((ext_vector_type(4)));

static __device__ __forceinline__ float bf2f(short u) {
  union { unsigned int i; float f; } x;
  x.i = ((unsigned int)(unsigned short)u) << 16;
  return x.f;
}
static __device__ __forceinline__ short f2bf(float f) {
  union { unsigned int i; float f; } x;
  x.f = f;
  unsigned int r = x.i + 0x7fffu + ((x.i >> 16) & 1u);  // RNE
  return (short)(r >> 16);
}
// HW packed f32->bf16 (RNE): lo16 = bf16(a), hi16 = bf16(b)
static __device__ __forceinline__ unsigned cvtpk(float a, float b) {
  unsigned r;
  asm("v_cvt_pk_bf16_f32 %0, %1, %2" : "=v"(r) : "v"(a), "v"(b));
  return r;
}

// async global->LDS, 16B per lane; lds base wave-uniform (HW adds lane*16)
static __device__ __forceinline__ void gload16(const short* g, short* l) {
  __builtin_amdgcn_global_load_lds((const __attribute__((address_space(1))) void*)g,
                                   (__attribute__((address_space(3))) void*)l, 16, 0, 0);
}

// ---------------- fp32 -> bf16 converts + RoPE table in one launch ----------------
// grid (1024, 9): y<4 -> x slices, y 4..7 -> weights, y==8 -> cos/sin table.
__global__ void cvt_all(const float* __restrict__ x, const float* __restrict__ w0,
                        const float* __restrict__ w1, const float* __restrict__ w2,
                        const float* __restrict__ w3, short* __restrict__ xb,
                        short* __restrict__ o0, short* __restrict__ o1,
                        short* __restrict__ o2, short* __restrict__ o3,
                        float2* __restrict__ tab) {
  int y = blockIdx.y;
  if (y == 8) {  // RoPE cos/sin table: [2048 pos][32 freq]
    if (blockIdx.x < 256) {
      int idx = blockIdx.x * 256 + threadIdx.x;  // pos*32 + j
      int pos = idx >> 5, j = idx & 31;
      float freq = powf(10000.0f, -(float)j / 32.0f);  // theta^(-2j/64)
      float ang = (float)pos * freq;
      tab[idx] = make_float2(cosf(ang), sinf(ang));
    }
    return;
  }
  const float* in;
  short* out;
  if (y < 4) { in = x + (size_t)y * DM * DM; out = xb + (size_t)y * DM * DM; }
  else if (y == 4) { in = w0; out = o0; }
  else if (y == 5) { in = w1; out = o1; }
  else if (y == 6) { in = w2; out = o2; }
  else { in = w3; out = o3; }
  int i = (blockIdx.x * blockDim.x + threadIdx.x) * 4;
  float4 v = *reinterpret_cast<const float4*>(in + i);
  short4 o;
  o.x = f2bf(v.x); o.y = f2bf(v.y); o.z = f2bf(v.z); o.w = f2bf(v.w);
  *reinterpret_cast<short4*>(out + i) = o;
}

// ---------------- RoPE apply, vectorized bf16x8 (4 pairs/thread) ----------------
// Q additionally pre-scaled by 0.125*log2(e) (softmax works in exp2 domain).
__global__ void rope_apply_kernel(short* __restrict__ Qb, short* __restrict__ Kb,
                                  const int* __restrict__ pos, const float2* __restrict__ tab) {
  short* buf = blockIdx.y ? Kb : Qb;
  const float scale = blockIdx.y ? 1.0f : 0.1803368801f;  // 0.125*log2e
  int gid = blockIdx.x * blockDim.x + threadIdx.x;        // [0, NR*DM/8)
  int elem = gid * 8;
  int row = elem >> 10, off = elem & 1023;
  int j0 = (off & 63) >> 1;
  short* ptr = buf + (size_t)row * DM + off;
  bf16x8 v = *reinterpret_cast<bf16x8*>(ptr);
  const float2* tp = &tab[pos[row] * 32 + j0];
  bf16x8 o;
#pragma unroll
  for (int q = 0; q < 4; ++q) {
    float2 cs = tp[q];
    float xe = bf2f(v[2 * q]), xo = bf2f(v[2 * q + 1]);
    o[2 * q] = f2bf((xe * cs.x - xo * cs.y) * scale);
    o[2 * q + 1] = f2bf((xe * cs.y + xo * cs.x) * scale);
  }
  *reinterpret_cast<bf16x8*>(ptr) = o;
}

// ---------------- V transpose: V[b*S+s][h*64+d] -> Vt[(bh*64+d)][s] ----------------
__global__ __launch_bounds__(256) void vt_transpose_kernel(const short* __restrict__ V,
                                                           short* __restrict__ Vt) {
  __shared__ short tile[64][64];
  const int t = threadIdx.x;
  const int bh = blockIdx.y, b = bh >> 4, h = bh & 15;
  const int st = blockIdx.x * 64;
#pragma unroll
  for (int p = 0; p < 2; ++p) {
    int c = p * 256 + t;
    int srow = c >> 3, ch = c & 7;
    int chs = ch ^ ((srow >> 3) & 7);  // swizzle chunk index
    *reinterpret_cast<bf16x8*>(&tile[srow][chs * 8]) =
        *reinterpret_cast<const bf16x8*>(&V[(size_t)(b * SEQL + st + srow) * DM + h * 64 + ch * 8]);
  }
  __syncthreads();
#pragma unroll
  for (int p = 0; p < 2; ++p) {
    int c = p * 256 + t;
    int drow = c >> 3, soff = (c & 7) * 8;
    short o[8];
#pragma unroll
    for (int e = 0; e < 8; ++e) {
      int srow = soff + e;
      int col = (((drow >> 3) ^ ((srow >> 3) & 7)) << 3) + (drow & 7);
      o[e] = tile[srow][col];
    }
    *reinterpret_cast<bf16x8*>(&Vt[(size_t)(bh * DK + drow) * SEQL + st + soff]) =
        *reinterpret_cast<bf16x8*>(o);
  }
}

// ---------------- bf16 GEMM core: BK=64 on the PASSED 2-syncthreads template ----------------
static __device__ __forceinline__ void gemm_core(const short* __restrict__ A,
                                                 const short* __restrict__ B,
                                                 int m0, int n0, int K,
                                                 f32x4 (&acc)[4][4]) {
  __shared__ short As[2][128][32];
  __shared__ short Bs[2][128][32];
  const int t = threadIdx.x;
  const int wid = t >> 6, lane = t & 63;
  const int wr = wid >> 1, wc = wid & 1;
  const int lrow = lane & 15, lk = lane >> 4;

#pragma unroll
  for (int i = 0; i < 4; ++i)
#pragma unroll
    for (int j = 0; j < 4; ++j) acc[i][j] = (f32x4){0.f, 0.f, 0.f, 0.f};

  for (int k0 = 0; k0 < K; k0 += 64) {
    __syncthreads();
#pragma unroll
    for (int hp = 0; hp < 2; ++hp)
#pragma unroll
      for (int p = 0; p < 2; ++p) {
        int c = p * 256 + t;            // 512 chunks of 8 bf16 = 128x32 per half
        int row = c >> 2, kc = (c & 3) * 8;
        gload16(&A[(size_t)(m0 + row) * K + k0 + hp * 32 + kc],
                &As[hp][0][0] + (size_t)(p * 256 + wid * 64) * 8);
        gload16(&B[(size_t)(n0 + row) * K + k0 + hp * 32 + kc],
                &Bs[hp][0][0] + (size_t)(p * 256 + wid * 64) * 8);
      }
    __syncthreads();
#pragma unroll
    for (int hp = 0; hp < 2; ++hp) {
      bf16x8 af[4], bfr[4];
#pragma unroll
      for (int i = 0; i < 4; ++i) {
        af[i] = *reinterpret_cast<const bf16x8*>(&As[hp][wr * 64 + i * 16 + lrow][lk * 8]);
        bfr[i] = *reinterpret_cast<const bf16x8*>(&Bs[hp][wc * 64 + i * 16 + lrow][lk * 8]);
      }
      __builtin_amdgcn_s_setprio(1);
#pragma unroll
      for (int i = 0; i < 4; ++i)
#pragma unroll
        for (int j = 0; j < 4; ++j)
          acc[i][j] = __builtin_amdgcn_mfma_f32_16x16x32_bf16(af[i], bfr[j], acc[i][j], 0, 0, 0);
      __builtin_amdgcn_s_setprio(0);
    }
  }
}

// ---------------- QKV GEMM; plain coalesced bf16 stores ----------------
// grid 768 flat; XCD-aware decode: each XCD owns 3 fixed B-panels (L2-resident).
__global__ __launch_bounds__(256) void qkv_gemm_kernel(
    const short* __restrict__ X, const short* __restrict__ Wq, const short* __restrict__ Wk,
    const short* __restrict__ Wv, short* __restrict__ Qb, short* __restrict__ Kb,
    short* __restrict__ Vb) {
  const int lin = blockIdx.x;             // 0..767
  const int xcd = lin & 7, i = lin >> 3;  // i 0..95
  const int nb = xcd * 3 + (i % 3);       // 0..23
  const int my = i / 3;                   // 0..31
  const short* Bw = (nb < 8) ? Wq : (nb < 16) ? Wk : Wv;
  short* C = (nb < 8) ? Qb : (nb < 16) ? Kb : Vb;
  const int m0 = my * 128, n0 = (nb & 7) * 128;
  f32x4 acc[4][4];
  gemm_core(X, Bw, m0, n0, DM, acc);

  const int t = threadIdx.x;
  const int wid = t >> 6, lane = t & 63;
  const int wr = wid >> 1, wc = wid & 1;
  const int lrow = lane & 15, lk = lane >> 4;
#pragma unroll
  for (int i2 = 0; i2 < 4; ++i2)
#pragma unroll
    for (int j = 0; j < 4; ++j) {
      int row = m0 + wr * 64 + i2 * 16 + lk * 4;
      int col = n0 + wc * 64 + j * 16 + lrow;
#pragma unroll
      for (int r = 0; r < 4; ++r) C[(size_t)(row + r) * DM + col] = f2bf(acc[i2][j][r]);
    }
}

// grid 256 flat; each XCD owns exactly one B-panel.
__global__ __launch_bounds__(256) void out_gemm_kernel(const short* __restrict__ A,
                                                       const short* __restrict__ W,
                                                       float* __restrict__ C) {
  const int lin = blockIdx.x;  // 0..255
  const int m0 = (lin >> 3) * 128, n0 = (lin & 7) * 128;
  f32x4 acc[4][4];
  gemm_core(A, W, m0, n0, DM, acc);
  const int t = threadIdx.x;
  const int wid = t >> 6, lane = t & 63;
  const int wr = wid >> 1, wc = wid & 1;
  const int lrow = lane & 15, lk = lane >> 4;
#pragma unroll
  for (int i = 0; i < 4; ++i)
#pragma unroll
    for (int j = 0; j < 4; ++j) {
      int row = m0 + wr * 64 + i * 16 + lk * 4;
      int col = n0 + wc * 64 + j * 16 + lrow;
#pragma unroll
      for (int r = 0; r < 4; ++r) C[(size_t)(row + r) * DM + col] = acc[i][j][r];
    }
}

// ---------------- causal flash attention (K-row-permuted, LDS-free P path) ----------------
// Round-16 PASSED structure; single change: Ks rows are staged PERMUTED
// (kperm(rv) = (g&1)*32 + (m>>2)*8 + (g>>1)*4 + (m&3), rv = g*16+m, bijective per tile)
// so the QK^T C-layout output is ALREADY in PV A-fragment order:
//   pa0 = {cvtpk(st[0]), cvtpk(st[2])}, pa1 = {cvtpk(st[1]), cvtpk(st[3])}  (own lane only).
// PV contraction is over k, P and V agree on the (physical) k order, V path untouched.
// Deletes Ps LDS (55.3->36.9KB), the ds_write/lgkmcnt(0)/ds_read chain, and sched_barrier.
// Causal mask uses the physical k: kphys = (g&1)*32 + lk*8 + (g>>1)*4 + r.
__global__ __launch_bounds__(512) void attn_kernel(const short* __restrict__ Q,
                                                   const short* __restrict__ K,
                                                   const short* __restrict__ Vt,
                                                   short* __restrict__ O) {
  __shared__ short Ks[2][64][72];
  __shared__ short Vs[2][64][72];
  const int t = threadIdx.x;
  const int wid = t >> 6, lane = t & 63;
  const int lrow = lane & 15, lk = lane >> 4;
  const int lin = blockIdx.x;            // 0..511
  const int xcd = lin & 7, idx = lin >> 3;  // idx 0..63
  // long blocks (qt 15..8) dispatch first; complement (qt 0..7) second
  const int qt = (idx < 32) ? (15 - (idx >> 2)) : ((idx - 32) >> 2);
  const int bh = xcd * 4 + (idx & 3);    // 4 bh per XCD (K/V/Q fit L2)
  const int b = bh >> 4, h = bh & 15;
  const size_t base = (size_t)b * SEQL * DM + (size_t)h * DK;  // Q,K,O
  const size_t vbase = (size_t)bh * DK * SEQL;                 // Vt
  const int kr = t >> 3, ko = (t & 7) * 8;  // staging: 1 chunk/thread (512 thr = 64x64)
  // permuted source row for Ks staging (bijective within the 64-row tile)
  const int kpr = ((kr >> 4) & 1) * 32 + (((kr & 15) >> 2) * 8) + ((kr >> 5) * 4) + (kr & 3);
  const int ktmax = 2 * qt + 1;
  const int qmin = qt * 128 + wid * 16;
  const int dkt = qmin >> 6;   // wave's diagonal k-tile

  bf16x8 aq[2];
#pragma unroll
  for (int c = 0; c < 2; ++c)
    aq[c] = *reinterpret_cast<const bf16x8*>(
        &Q[base + (size_t)(qmin + lrow) * DM + c * 32 + lk * 8]);

  // ones B-fragment for the row-sum MFMA
  bf16x8 vones;
#pragma unroll
  for (int e = 0; e < 8; ++e) vones[e] = (short)0x3F80;

  f32x4 oacc[4];
#pragma unroll
  for (int g = 0; g < 4; ++g) oacc[g] = (f32x4){0.f, 0.f, 0.f, 0.f};
  f32x4 oaccL = (f32x4){0.f, 0.f, 0.f, 0.f};  // row-sum (lsum) accumulator

  // prologue: stage tile 0 into buf 0 (K rows permuted at the global source)
  {
    bf16x8 k0 = *reinterpret_cast<const bf16x8*>(&K[base + (size_t)kpr * DM + ko]);
    bf16x8 v0 = *reinterpret_cast<const bf16x8*>(&Vt[vbase + (size_t)kr * SEQL + ko]);
    *reinterpret_cast<bf16x8*>(&Ks[0][kr][ko]) = k0;
    *reinterpret_cast<bf16x8*>(&Vs[0][kr][ko]) = v0;
  }
  __syncthreads();
  int cur = 0;
  bf16x8 kreg, vreg;
  for (int kt = 0; kt <= ktmax; ++kt) {
    // buf[cur] holds tile kt (visible since last barrier)
    if (kt < ktmax) {  // T14: issue next tile's loads; latency hides under compute
      size_t kof = (size_t)(kt + 1) * 64;
      kreg = *reinterpret_cast<const bf16x8*>(&K[base + (kof + kpr) * DM + ko]);
      vreg = *reinterpret_cast<const bf16x8*>(&Vt[vbase + (size_t)kr * SEQL + kof + ko]);
    }
    if (kt <= dkt) {  // wave-uniform active gate
      // S^T = K Q^T : lane holds S[q=qmin+lrow][kphys=(g&1)*32+lk*8+(g>>1)*4+r] (exp2 domain)
      f32x4 st[4];
      __builtin_amdgcn_s_setprio(1);
#pragma unroll
      for (int g = 0; g < 4; ++g) {
        bf16x8 kf0 = *reinterpret_cast<const bf16x8*>(&Ks[cur][g * 16 + lrow][lk * 8]);
        bf16x8 kf1 = *reinterpret_cast<const bf16x8*>(&Ks[cur][g * 16 + lrow][32 + lk * 8]);
        f32x4 z = (f32x4){0.f, 0.f, 0.f, 0.f};
        z = __builtin_amdgcn_mfma_f32_16x16x32_bf16(kf0, aq[0], z, 0, 0, 0);
        st[g] = __builtin_amdgcn_mfma_f32_16x16x32_bf16(kf1, aq[1], z, 0, 0, 0);
      }
      __builtin_amdgcn_s_setprio(0);
      const int qg = qmin + lrow;
      if (kt == dkt) {  // diagonal tile masking (physical k index)
#pragma unroll
        for (int g = 0; g < 4; ++g)
#pragma unroll
          for (int r = 0; r < 4; ++r)
            if (kt * 64 + (g & 1) * 32 + lk * 8 + ((g >> 1) * 4) + r > qg) st[g][r] = -1e30f;
      }
      // P = exp2(st) directly (no shift, no max tracking)
#pragma unroll
      for (int g = 0; g < 4; ++g)
#pragma unroll
        for (int r = 0; r < 4; ++r) st[g][r] = exp2f(st[g][r]);
      // P -> A-fragments: pure own-lane packing (k-permutation made C-layout A-ordered)
      union { bf16x8 v; unsigned u[4]; } pa0u, pa1u;
      pa0u.u[0] = cvtpk(st[0][0], st[0][1]);
      pa0u.u[1] = cvtpk(st[0][2], st[0][3]);
      pa0u.u[2] = cvtpk(st[2][0], st[2][1]);
      pa0u.u[3] = cvtpk(st[2][2], st[2][3]);
      pa1u.u[0] = cvtpk(st[1][0], st[1][1]);
      pa1u.u[1] = cvtpk(st[1][2], st[1][3]);
      pa1u.u[2] = cvtpk(st[3][0], st[3][1]);
      pa1u.u[3] = cvtpk(st[3][2], st[3][3]);
      const bf16x8 pa0 = pa0u.v, pa1 = pa1u.v;
      __builtin_amdgcn_s_setprio(1);
#pragma unroll
      for (int g = 0; g < 4; ++g) {
        bf16x8 vf0 = *reinterpret_cast<const bf16x8*>(&Vs[cur][g * 16 + lrow][lk * 8]);
        bf16x8 vf1 = *reinterpret_cast<const bf16x8*>(&Vs[cur][g * 16 + lrow][32 + lk * 8]);
        oacc[g] = __builtin_amdgcn_mfma_f32_16x16x32_bf16(pa0, vf0, oacc[g], 0, 0, 0);
        oacc[g] = __builtin_amdgcn_mfma_f32_16x16x32_bf16(pa1, vf1, oacc[g], 0, 0, 0);
      }
      // row-sum of P via ones-column MFMA -> lsum in accumulator layout
      oaccL = __builtin_amdgcn_mfma_f32_16x16x32_bf16(pa0, vones, oaccL, 0, 0, 0);
      oaccL = __builtin_amdgcn_mfma_f32_16x16x32_bf16(pa1, vones, oaccL, 0, 0, 0);
      __builtin_amdgcn_s_setprio(0);
    }
    if (kt < ktmax) {  // write next tile into the idle buffer (safe pre-barrier)
      *reinterpret_cast<bf16x8*>(&Ks[cur ^ 1][kr][ko]) = kreg;
      *reinterpret_cast<bf16x8*>(&Vs[cur ^ 1][kr][ko]) = vreg;
    }
    __syncthreads();  // single barrier: publishes buf[cur^1], retires buf[cur] readers
    cur ^= 1;
  }
  // epilogue: normalize — lsum already per-row in oaccL[r], no cross-lane ops
  float lr[4];
#pragma unroll
  for (int r = 0; r < 4; ++r) lr[r] = 1.0f / oaccL[r];
#pragma unroll
  for (int g = 0; g < 4; ++g)
#pragma unroll
    for (int r = 0; r < 4; ++r)
      O[base + (size_t)(qmin + lk * 4 + r) * DM + g * 16 + lrow] = f2bf(oacc[g][r] * lr[r]);
}

// ---------------- host launch ----------------
extern "C" void kernel_launch(void* const* d_in, const int* in_sizes, int n_in,
                              void* d_out, int out_size, void* d_ws, size_t ws_size,
                              hipStream_t stream) {
  const float* x = (const float*)d_in[0];
  const float* wq = (const float*)d_in[1];
  const float* wk = (const float*)d_in[2];
  const float* wv = (const float*)d_in[3];
  const float* wo = (const float*)d_in[4];
  const int* tpos = (const int*)d_in[5];
  float* out = (float*)d_out;

  char* w = (char*)d_ws;
  short* xb = (short*)w;  w += (size_t)NR * DM * 2;
  short* wqb = (short*)w; w += (size_t)DM * DM * 2;
  short* wkb = (short*)w; w += (size_t)DM * DM * 2;
  short* wvb = (short*)w; w += (size_t)DM * DM * 2;
  short* wob = (short*)w; w += (size_t)DM * DM * 2;
  short* Qb = (short*)w;  w += (size_t)NR * DM * 2;
  short* Kb = (short*)w;  w += (size_t)NR * DM * 2;
  short* Vb = (short*)w;  w += (size_t)NR * DM * 2;
  short* Ob = (short*)w;  w += (size_t)NR * DM * 2;
  float2* tab = (float2*)w;
  short* Vtb = xb;  // alias: xb's last use is qkv_gemm; Vt produced after

  cvt_all<<<dim3(DM * DM / 1024, 9), 256, 0, stream>>>(x, wq, wk, wv, wo, xb, wqb, wkb, wvb,
                                                       wob, tab);
  qkv_gemm_kernel<<<768, 256, 0, stream>>>(xb, wqb, wkb, wvb, Qb, Kb, Vb);
  rope_apply_kernel<<<dim3(NR * DM / 8 / 256, 2), 256, 0, stream>>>(Qb, Kb, tpos, tab);
  vt_transpose_kernel<<<dim3(SEQL / 64, NB * NH), 256, 0, stream>>>(Vb, Vtb);
  attn_kernel<<<512, 512, 0, stream>>>(Qb, Kb, Vtb, Ob);
  out_gemm_kernel<<<256, 256, 0, stream>>>(Ob, wob, out);
}